// Round 1
// 117.949 us; speedup vs baseline: 1.0282x; 1.0282x over previous
//
#include <hip/hip_runtime.h>

#define IMG   512
#define NIMG  32
#define TX    128
#define TY    16
#define NQ    36                  /* staged quad strips per block */
#define VQS   17                  /* sV strip stride in quads (16 rows + 1 pad) */
#define VPL   (NQ * VQS)          /* 612 quads per channel plane */
#define VITEMS (NQ * 8)           /* 288 v-pass items */
#define NCH   4                   /* a, b, a^2+b^2, ab */
#define NBX   (IMG / TX)          /* 4 */
#define NBY   (IMG / TY)          /* 32 */
#define NBLK  (NBX * NBY * NIMG)  /* 4096 */
#define NPIX  (32.0f * 512.0f * 512.0f)

constexpr float GW[11] = {
    0.00102838f, 0.00759876f, 0.03600077f, 0.10936069f, 0.21300553f,
    0.26601174f,
    0.21300553f, 0.10936069f, 0.03600077f, 0.00759876f, 0.00102838f
};
constexpr float C1c = 0.0001f;
constexpr float C2c = 0.0009f;

__global__ void ssim_init_out(float* __restrict__ out) { out[0] = 1.0f; }

__device__ __forceinline__ float4 f4mul(float4 a, float4 b) {
    return make_float4(a.x * b.x, a.y * b.y, a.z * b.z, a.w * b.w);
}
__device__ __forceinline__ float4 f4fma(float w, float4 v, float4 c) {
    return make_float4(fmaf(w, v.x, c.x), fmaf(w, v.y, c.y),
                       fmaf(w, v.z, c.z), fmaf(w, v.w, c.w));
}
__device__ __forceinline__ float4 f4fma_v(float4 a, float4 b, float4 c) {
    return make_float4(fmaf(a.x, b.x, c.x), fmaf(a.y, b.y, c.y),
                       fmaf(a.z, b.z, c.z), fmaf(a.w, b.w, c.w));
}

// One v-pass item: strip q, row-pair g. Computes NCH vertical convs for 2
// output rows of one float4 column strip, writes to transposed sV.
// Channels: 0 = a, 1 = b, 2 = a^2+b^2, 3 = ab  (SSIM only needs the SUM of
// the two squared-moment convs, so a^2 and b^2 are fused pre-conv).
// INTERIOR: no bounds code at all. Boundary: clamped addresses (always
// valid) + weight-kill (exact zero-pad semantics).
template <bool INTERIOR>
__device__ __forceinline__ void vpass_item(int it, int X0, int Y0,
        const float* __restrict__ a0, const float* __restrict__ b0,
        float4* __restrict__ sV4) {
    const int q  = it % NQ;
    const int g  = it / NQ;
    const int y0 = 2 * g;
    int gx0 = X0 - 8 + 4 * q;
    const int gyb = Y0 + y0 - 5;
    bool okx = true;
    if (!INTERIOR) {
        okx = (gx0 >= 0) && (gx0 + 3 < IMG);
        gx0 = min(max(gx0, 0), IMG - 4);
    }

    float4 acc[NCH][2];
#pragma unroll
    for (int ch = 0; ch < NCH; ++ch)
#pragma unroll
        for (int o = 0; o < 2; ++o)
            acc[ch][o] = make_float4(0.f, 0.f, 0.f, 0.f);

    float4 ra[6], rb[6];
#pragma unroll
    for (int half = 0; half < 2; ++half) {
        // batch-issue 12 loads (6 rows x 2 images), addresses always valid
#pragma unroll
        for (int j = 0; j < 6; ++j) {
            int gy = gyb + half * 6 + j;
            if (!INTERIOR) gy = min(max(gy, 0), IMG - 1);
            const int off = gy * IMG + gx0;
            ra[j] = *(const float4*)(a0 + off);
            rb[j] = *(const float4*)(b0 + off);
        }
#pragma unroll
        for (int j = 0; j < 6; ++j) {
            const int k = half * 6 + j;
            const float4 a  = ra[j];
            const float4 b  = rb[j];
            const float4 sq = f4fma_v(a, a, f4mul(b, b));   // a^2 + b^2
            const float4 ab = f4mul(a, b);
            if (INTERIOR) {
                if (k <= 10) {
                    const float w = GW[k];
                    acc[0][0] = f4fma(w, a,  acc[0][0]);
                    acc[1][0] = f4fma(w, b,  acc[1][0]);
                    acc[2][0] = f4fma(w, sq, acc[2][0]);
                    acc[3][0] = f4fma(w, ab, acc[3][0]);
                }
                if (k >= 1) {
                    const float w = GW[k - 1];
                    acc[0][1] = f4fma(w, a,  acc[0][1]);
                    acc[1][1] = f4fma(w, b,  acc[1][1]);
                    acc[2][1] = f4fma(w, sq, acc[2][1]);
                    acc[3][1] = f4fma(w, ab, acc[3][1]);
                }
            } else {
                const int gy = gyb + k;
                const bool ok = okx && ((unsigned)gy < IMG);
                float w0 = (k <= 10) ? GW[k] : 0.0f;
                float w1 = (k >= 1) ? GW[k - 1] : 0.0f;
                w0 = ok ? w0 : 0.0f;
                w1 = ok ? w1 : 0.0f;
                acc[0][0] = f4fma(w0, a,  acc[0][0]);
                acc[1][0] = f4fma(w0, b,  acc[1][0]);
                acc[2][0] = f4fma(w0, sq, acc[2][0]);
                acc[3][0] = f4fma(w0, ab, acc[3][0]);
                acc[0][1] = f4fma(w1, a,  acc[0][1]);
                acc[1][1] = f4fma(w1, b,  acc[1][1]);
                acc[2][1] = f4fma(w1, sq, acc[2][1]);
                acc[3][1] = f4fma(w1, ab, acc[3][1]);
            }
        }
    }
#pragma unroll
    for (int o = 0; o < 2; ++o)
#pragma unroll
        for (int ch = 0; ch < NCH; ++ch)
            sV4[ch * VPL + q * VQS + (y0 + o)] = acc[ch][o];
}

__global__ __launch_bounds__(256, 4) void ssim_fused(
        const float* __restrict__ img1, const float* __restrict__ img2,
        float* __restrict__ ws, float* __restrict__ out) {
    // sV transposed [ch][strip q][row y]: 4*612 quads * 16B = 39.17 KB
    // -> 4 blocks/CU (was 3 at 5 channels), grid = exactly 4 full CU-passes.
    __shared__ float4 sV4[NCH * VPL];

    const int tid = threadIdx.x;
    const int X0 = blockIdx.x * TX;
    const int Y0 = blockIdx.y * TY;
    const int n  = blockIdx.z;
    const float* a0 = img1 + (size_t)n * IMG * IMG;
    const float* b0 = img2 + (size_t)n * IMG * IMG;

    // Interior iff every load address is naturally in-bounds.
    const bool interior = (X0 >= 8) && (X0 - 8 + 4 * (NQ - 1) + 3 < IMG) &&
                          (Y0 >= 5) && (Y0 + TY + 4 < IMG);

    if (interior) {
        for (int it = tid; it < VITEMS; it += 256)
            vpass_item<true>(it, X0, Y0, a0, b0, sV4);
    } else {
        for (int it = tid; it < VITEMS; it += 256)
            vpass_item<false>(it, X0, Y0, a0, b0, sV4);
    }
    __syncthreads();

    // ---- horizontal pass + ssim: 8 output cols/thread, 256 items exactly.
    // 8-lane phase: y consecutive, strip fixed -> conflict-free b128.
    float sum = 0.0f;
    {
        const int y   = tid & 15;      // row 0..15
        const int grp = tid >> 4;      // 8-col group: out cols 8*grp..8*grp+7
        float res[NCH][8];
#pragma unroll
        for (int ch = 0; ch < NCH; ++ch) {
            const float4* base = &sV4[ch * VPL + y];
            float v[24];
#pragma unroll
            for (int d = 0; d < 6; ++d) {
                const float4 t = base[(2 * grp + d) * VQS];
                v[4 * d + 0] = t.x; v[4 * d + 1] = t.y;
                v[4 * d + 2] = t.z; v[4 * d + 3] = t.w;
            }
#pragma unroll
            for (int e = 0; e < 8; ++e) {
                float s = GW[0] * v[e + 3];
#pragma unroll
                for (int k = 1; k < 11; ++k) s = fmaf(GW[k], v[e + 3 + k], s);
                res[ch][e] = s;
            }
        }
#pragma unroll
        for (int e = 0; e < 8; ++e) {
            const float mu1 = res[0][e], mu2 = res[1][e];
            const float m1s = mu1 * mu1;
            const float m2s = mu2 * mu2;
            const float m12 = mu1 * mu2;
            const float msum = m1s + m2s;
            const float ssum = res[2][e] - msum;   // sigma1_sq + sigma2_sq
            const float s12  = res[3][e] - m12;
            const float num = (2.0f * m12 + C1c) * (2.0f * s12 + C2c);
            const float den = (msum + C1c) * (ssum + C2c);
            sum += num * __builtin_amdgcn_rcpf(den);
        }
    }

    // ---- block reduction ----
#pragma unroll
    for (int off = 32; off > 0; off >>= 1)
        sum += __shfl_down(sum, off, 64);

    __shared__ float wred[4];
    if ((tid & 63) == 0) wred[tid >> 6] = sum;
    __syncthreads();
    if (tid == 0) {
        const float s = wred[0] + wred[1] + wred[2] + wred[3];
        if (ws) {
            const int bid = blockIdx.x +
                (int)gridDim.x * (blockIdx.y + (int)gridDim.y * blockIdx.z);
            ws[bid] = s;
        } else {
            atomicAdd(out, -s * (1.0f / NPIX));
        }
    }
}

__global__ __launch_bounds__(1024) void ssim_reduce(
        const float* __restrict__ ws, float* __restrict__ out) {
    const int t = threadIdx.x;
    float s = 0.0f;
    for (int i = t; i < NBLK; i += 1024) s += ws[i];
#pragma unroll
    for (int off = 32; off > 0; off >>= 1)
        s += __shfl_down(s, off, 64);
    __shared__ float wr[16];
    if ((t & 63) == 0) wr[t >> 6] = s;
    __syncthreads();
    if (t < 64) {
        float v = (t < 16) ? wr[t] : 0.0f;
#pragma unroll
        for (int off = 8; off > 0; off >>= 1)
            v += __shfl_down(v, off, 64);
        if (t == 0) out[0] = 1.0f - v * (1.0f / NPIX);
    }
}

extern "C" void kernel_launch(void* const* d_in, const int* in_sizes, int n_in,
                              void* d_out, int out_size, void* d_ws, size_t ws_size,
                              hipStream_t stream) {
    const float* img1 = (const float*)d_in[0];
    const float* img2 = (const float*)d_in[1];
    float* out = (float*)d_out;
    const bool two_stage = (d_ws != nullptr) && (ws_size >= NBLK * sizeof(float));
    float* ws = two_stage ? (float*)d_ws : nullptr;

    if (!two_stage) ssim_init_out<<<1, 1, 0, stream>>>(out);

    dim3 grid(NBX, NBY, NIMG);   // 4 x 32 x 32 = 4096 blocks
    ssim_fused<<<grid, 256, 0, stream>>>(img1, img2, ws, out);

    if (two_stage) ssim_reduce<<<1, 1024, 0, stream>>>(ws, out);
}

// Round 2
// 117.208 us; speedup vs baseline: 1.0347x; 1.0063x over previous
//
#include <hip/hip_runtime.h>

#define IMG   512
#define NIMG  32
#define TX    128
#define TY    16
#define NQ    36                  /* staged quad strips per block */
#define VQS   17                  /* sV strip stride in quads (16 rows + 1 pad) */
#define VPL   (NQ * VQS)          /* 612 quads per channel plane */
#define VITEMS (NQ * 8)           /* 288 v-pass items */
#define NCH   4                   /* a, b, a^2+b^2, ab */
#define NBX   (IMG / TX)          /* 4 */
#define NBY   (IMG / TY)          /* 32 */
#define NBLK  (NBX * NBY * NIMG)  /* 4096 */
#define NPIX  (32.0f * 512.0f * 512.0f)

constexpr float GW[11] = {
    0.00102838f, 0.00759876f, 0.03600077f, 0.10936069f, 0.21300553f,
    0.26601174f,
    0.21300553f, 0.10936069f, 0.03600077f, 0.00759876f, 0.00102838f
};
constexpr float C1c = 0.0001f;
constexpr float C2c = 0.0009f;

__global__ void ssim_init_out(float* __restrict__ out) { out[0] = 1.0f; }

__device__ __forceinline__ float4 f4mul(float4 a, float4 b) {
    return make_float4(a.x * b.x, a.y * b.y, a.z * b.z, a.w * b.w);
}
__device__ __forceinline__ float4 f4fma(float w, float4 v, float4 c) {
    return make_float4(fmaf(w, v.x, c.x), fmaf(w, v.y, c.y),
                       fmaf(w, v.z, c.z), fmaf(w, v.w, c.w));
}
__device__ __forceinline__ float4 f4fma_v(float4 a, float4 b, float4 c) {
    return make_float4(fmaf(a.x, b.x, c.x), fmaf(a.y, b.y, c.y),
                       fmaf(a.z, b.z, c.z), fmaf(a.w, b.w, c.w));
}

// One v-pass item: strip q, row-pair g. Computes NCH vertical convs for 2
// output rows of one float4 column strip, writes to transposed sV.
// Channels: 0 = a, 1 = b, 2 = a^2+b^2, 3 = ab.
// ALL 12 row-loads are issued as one batch before any compute: one vmcnt
// latency exposure per item instead of two (VGPR budget 128 at 4 waves/SIMD,
// and occupancy is LDS-bound anyway -> the extra ~56 VGPRs are free).
template <bool INTERIOR>
__device__ __forceinline__ void vpass_item(int it, int X0, int Y0,
        const float* __restrict__ a0, const float* __restrict__ b0,
        float4* __restrict__ sV4) {
    const int q  = it % NQ;
    const int g  = it / NQ;
    const int y0 = 2 * g;
    int gx0 = X0 - 8 + 4 * q;
    const int gyb = Y0 + y0 - 5;
    bool okx = true;
    if (!INTERIOR) {
        okx = (gx0 >= 0) && (gx0 + 3 < IMG);
        gx0 = min(max(gx0, 0), IMG - 4);
    }

    float4 ra[12], rb[12];
#pragma unroll
    for (int j = 0; j < 12; ++j) {
        int gy = gyb + j;
        if (!INTERIOR) gy = min(max(gy, 0), IMG - 1);
        const int off = gy * IMG + gx0;
        ra[j] = *(const float4*)(a0 + off);
        rb[j] = *(const float4*)(b0 + off);
    }

    float4 acc[NCH][2];
#pragma unroll
    for (int ch = 0; ch < NCH; ++ch)
#pragma unroll
        for (int o = 0; o < 2; ++o)
            acc[ch][o] = make_float4(0.f, 0.f, 0.f, 0.f);

#pragma unroll
    for (int k = 0; k < 12; ++k) {
        const float4 a  = ra[k];
        const float4 b  = rb[k];
        const float4 sq = f4fma_v(a, a, f4mul(b, b));   // a^2 + b^2
        const float4 ab = f4mul(a, b);
        if (INTERIOR) {
            if (k <= 10) {
                const float w = GW[k];
                acc[0][0] = f4fma(w, a,  acc[0][0]);
                acc[1][0] = f4fma(w, b,  acc[1][0]);
                acc[2][0] = f4fma(w, sq, acc[2][0]);
                acc[3][0] = f4fma(w, ab, acc[3][0]);
            }
            if (k >= 1) {
                const float w = GW[k - 1];
                acc[0][1] = f4fma(w, a,  acc[0][1]);
                acc[1][1] = f4fma(w, b,  acc[1][1]);
                acc[2][1] = f4fma(w, sq, acc[2][1]);
                acc[3][1] = f4fma(w, ab, acc[3][1]);
            }
        } else {
            const int gy = gyb + k;
            const bool ok = okx && ((unsigned)gy < IMG);
            float w0 = (k <= 10) ? GW[k] : 0.0f;
            float w1 = (k >= 1) ? GW[k - 1] : 0.0f;
            w0 = ok ? w0 : 0.0f;
            w1 = ok ? w1 : 0.0f;
            acc[0][0] = f4fma(w0, a,  acc[0][0]);
            acc[1][0] = f4fma(w0, b,  acc[1][0]);
            acc[2][0] = f4fma(w0, sq, acc[2][0]);
            acc[3][0] = f4fma(w0, ab, acc[3][0]);
            acc[0][1] = f4fma(w1, a,  acc[0][1]);
            acc[1][1] = f4fma(w1, b,  acc[1][1]);
            acc[2][1] = f4fma(w1, sq, acc[2][1]);
            acc[3][1] = f4fma(w1, ab, acc[3][1]);
        }
    }

#pragma unroll
    for (int o = 0; o < 2; ++o)
#pragma unroll
        for (int ch = 0; ch < NCH; ++ch)
            sV4[ch * VPL + q * VQS + (y0 + o)] = acc[ch][o];
}

__global__ __launch_bounds__(256, 4) void ssim_fused(
        const float* __restrict__ img1, const float* __restrict__ img2,
        float* __restrict__ ws, float* __restrict__ out) {
    // sV transposed [ch][strip q][row y]: 4*612 quads * 16B = 39.17 KB
    // -> 4 blocks/CU, grid = exactly 4 full CU-passes.
    __shared__ float4 sV4[NCH * VPL];

    const int tid = threadIdx.x;
    const int X0 = blockIdx.x * TX;
    const int Y0 = blockIdx.y * TY;
    const int n  = blockIdx.z;
    const float* a0 = img1 + (size_t)n * IMG * IMG;
    const float* b0 = img2 + (size_t)n * IMG * IMG;

    // Interior iff every load address is naturally in-bounds.
    const bool interior = (X0 >= 8) && (X0 - 8 + 4 * (NQ - 1) + 3 < IMG) &&
                          (Y0 >= 5) && (Y0 + TY + 4 < IMG);

    if (interior) {
        for (int it = tid; it < VITEMS; it += 256)
            vpass_item<true>(it, X0, Y0, a0, b0, sV4);
    } else {
        for (int it = tid; it < VITEMS; it += 256)
            vpass_item<false>(it, X0, Y0, a0, b0, sV4);
    }
    __syncthreads();

    // ---- horizontal pass + ssim: 8 output cols/thread, 256 items exactly.
    // 8-lane phase: y consecutive, strip fixed -> conflict-free b128.
    float sum = 0.0f;
    {
        const int y   = tid & 15;      // row 0..15
        const int grp = tid >> 4;      // 8-col group: out cols 8*grp..8*grp+7
        float res[NCH][8];
#pragma unroll
        for (int ch = 0; ch < NCH; ++ch) {
            const float4* base = &sV4[ch * VPL + y];
            float v[24];
#pragma unroll
            for (int d = 0; d < 6; ++d) {
                const float4 t = base[(2 * grp + d) * VQS];
                v[4 * d + 0] = t.x; v[4 * d + 1] = t.y;
                v[4 * d + 2] = t.z; v[4 * d + 3] = t.w;
            }
#pragma unroll
            for (int e = 0; e < 8; ++e) {
                float s = GW[0] * v[e + 3];
#pragma unroll
                for (int k = 1; k < 11; ++k) s = fmaf(GW[k], v[e + 3 + k], s);
                res[ch][e] = s;
            }
        }
#pragma unroll
        for (int e = 0; e < 8; ++e) {
            const float mu1 = res[0][e], mu2 = res[1][e];
            const float m1s = mu1 * mu1;
            const float m2s = mu2 * mu2;
            const float m12 = mu1 * mu2;
            const float msum = m1s + m2s;
            const float ssum = res[2][e] - msum;   // sigma1_sq + sigma2_sq
            const float s12  = res[3][e] - m12;
            const float num = (2.0f * m12 + C1c) * (2.0f * s12 + C2c);
            const float den = (msum + C1c) * (ssum + C2c);
            sum += num * __builtin_amdgcn_rcpf(den);
        }
    }

    // ---- block reduction ----
#pragma unroll
    for (int off = 32; off > 0; off >>= 1)
        sum += __shfl_down(sum, off, 64);

    __shared__ float wred[4];
    if ((tid & 63) == 0) wred[tid >> 6] = sum;
    __syncthreads();
    if (tid == 0) {
        const float s = wred[0] + wred[1] + wred[2] + wred[3];
        if (ws) {
            const int bid = blockIdx.x +
                (int)gridDim.x * (blockIdx.y + (int)gridDim.y * blockIdx.z);
            ws[bid] = s;
        } else {
            atomicAdd(out, -s * (1.0f / NPIX));
        }
    }
}

__global__ __launch_bounds__(1024) void ssim_reduce(
        const float* __restrict__ ws, float* __restrict__ out) {
    const int t = threadIdx.x;
    float s = 0.0f;
    for (int i = t; i < NBLK; i += 1024) s += ws[i];
#pragma unroll
    for (int off = 32; off > 0; off >>= 1)
        s += __shfl_down(s, off, 64);
    __shared__ float wr[16];
    if ((t & 63) == 0) wr[t >> 6] = s;
    __syncthreads();
    if (t < 64) {
        float v = (t < 16) ? wr[t] : 0.0f;
#pragma unroll
        for (int off = 8; off > 0; off >>= 1)
            v += __shfl_down(v, off, 64);
        if (t == 0) out[0] = 1.0f - v * (1.0f / NPIX);
    }
}

extern "C" void kernel_launch(void* const* d_in, const int* in_sizes, int n_in,
                              void* d_out, int out_size, void* d_ws, size_t ws_size,
                              hipStream_t stream) {
    const float* img1 = (const float*)d_in[0];
    const float* img2 = (const float*)d_in[1];
    float* out = (float*)d_out;
    const bool two_stage = (d_ws != nullptr) && (ws_size >= NBLK * sizeof(float));
    float* ws = two_stage ? (float*)d_ws : nullptr;

    if (!two_stage) ssim_init_out<<<1, 1, 0, stream>>>(out);

    dim3 grid(NBX, NBY, NIMG);   // 4 x 32 x 32 = 4096 blocks
    ssim_fused<<<grid, 256, 0, stream>>>(img1, img2, ws, out);

    if (two_stage) ssim_reduce<<<1, 1024, 0, stream>>>(ws, out);
}